// Round 6
// baseline (575.706 us; speedup 1.0000x reference)
//
#include <hip/hip_runtime.h>

#define DD 16
#define BB 8
#define NN 2048
#define WMAX 2.0f

typedef float vfloat4 __attribute__((ext_vector_type(4)));

// ---------------------------------------------------------------------------
// Main kernel — lane-remapped broadcast design.
// One block per presynaptic row e (2048 blocks x 256 threads).
// Wave lane layout: b = lane>>3 (batch), oi = lane&7 (float4 position).
//   - Per lane: cp[d]=xbar_pre[d][b][e], cd[d]=Xd[d][b][e] preloaded once
//     (32 VGPRs, reused across all 16 o-chunk iterations).
//   - Per o-chunk: the 8 b-groups read the SAME 128B dmap segment ->
//     hardware coalesces to one transaction + broadcast; dmap still fetched
//     exactly once from HBM overall.
//   - Accumulators are 2 float4 per lane (8 VGPRs) -> compiler can hoist all
//     16 independent dmap loads (MLP), unlike the acc[8]-array versions
//     where it sank loads and re-read dmap 8x from L2.
// ---------------------------------------------------------------------------
__global__ __launch_bounds__(256, 4) void clopath_main(
    const float* __restrict__ Xd,        // (D,B,N)
    const float* __restrict__ Xpost,     // (B,N)
    const float* __restrict__ xbar_pre,  // (D,B,N)
    const float* __restrict__ u_pot,     // (B,N)
    const float* __restrict__ u_dep,     // (B,N)
    const float* __restrict__ W,         // (B,N,N)
    const float* __restrict__ A_p,       // (N,N)
    const float* __restrict__ A_d,       // (N,N)
    const float* __restrict__ dmap,      // (D,N,N)
    float* __restrict__ out_W,           // (B,N,N)  pre-update copy
    float* __restrict__ out_Wnew)        // (B,N,N)
{
    const int e    = (int)blockIdx.x;            // 0..2047
    const int lane = (int)threadIdx.x & 63;
    const int wv   = (int)threadIdx.x >> 6;      // 0..3
    const int b    = lane >> 3;                  // 0..7
    const int oi   = (lane & 7) << 2;            // 0,4,..,28

    // Per-lane coefficient preload (once per block, L2-resident arrays).
    float cp[DD], cd[DD];
#pragma unroll
    for (int d = 0; d < DD; ++d) {
        cp[d] = xbar_pre[(d * BB + b) * NN + e];
        cd[d] = Xd[(d * BB + b) * NN + e];
    }

    const size_t eN   = (size_t)e * NN;
    const size_t bNN  = (size_t)b * NN * NN;
    const int    bN   = b * NN;

    // o-chunks: each wave covers 32 o's per iter; 4 waves -> 128 per block-iter.
    for (int it = 0; it < NN / 128; ++it) {      // 16 iterations
        const int o = it * 128 + wv * 32 + oi;
        const size_t eo = eN + o;

        vfloat4 accp = (vfloat4)(0.f);
        vfloat4 accd = (vfloat4)(0.f);
#pragma unroll
        for (int d = 0; d < DD; ++d) {
            const vfloat4 dmv = *reinterpret_cast<const vfloat4*>(
                dmap + (size_t)d * NN * NN + eo);
            accp = __builtin_elementwise_fma((vfloat4)(cp[d]), dmv, accp);
            accd = __builtin_elementwise_fma((vfloat4)(cd[d]), dmv, accd);
        }

        const vfloat4 ap = *reinterpret_cast<const vfloat4*>(A_p + eo);
        const vfloat4 ad = *reinterpret_cast<const vfloat4*>(A_d + eo);
        const int bo = bN + o;
        const vfloat4 xp = *reinterpret_cast<const vfloat4*>(Xpost + bo);
        const vfloat4 up = *reinterpret_cast<const vfloat4*>(u_pot + bo);
        const vfloat4 ud = *reinterpret_cast<const vfloat4*>(u_dep + bo);

        const size_t widx = bNN + eo;
        const vfloat4 w4 = *reinterpret_cast<const vfloat4*>(W + widx);

        const vfloat4 gp = xp * __builtin_elementwise_max(up, (vfloat4)(0.f));
        const vfloat4 gd = __builtin_elementwise_max(ud, (vfloat4)(0.f));
        const vfloat4 dw = accp * ap * gp - accd * ad * gd;
        const vfloat4 wn = __builtin_elementwise_min(
            __builtin_elementwise_max(w4 + dw, (vfloat4)(0.f)),
            (vfloat4)(WMAX));

        *reinterpret_cast<vfloat4*>(out_W + widx)    = w4;
        *reinterpret_cast<vfloat4*>(out_Wnew + widx) = wn;
    }
}

// ---------------------------------------------------------------------------
// Trace-filter kernel: xbar_pre_new, u_pot_new, u_dep_new (all tiny).
// ---------------------------------------------------------------------------
__global__ __launch_bounds__(256) void clopath_traces(
    const float* __restrict__ Xd,        // (D,B,N)
    const float* __restrict__ Vpost,     // (B,N)
    const float* __restrict__ xbar_pre,  // (D,B,N)
    const float* __restrict__ u_pot,     // (B,N)
    const float* __restrict__ u_dep,     // (B,N)
    float* __restrict__ out_xbar,        // (D,B,N)
    float* __restrict__ out_upot,        // (B,N)
    float* __restrict__ out_udep)        // (B,N)
{
    const int NXB = DD * BB * NN;  // 262144
    const int NU  = BB * NN;       // 16384
    int i = ((int)blockIdx.x * 256 + (int)threadIdx.x) * 4;
    if (i < NXB) {
        const vfloat4 xb = *reinterpret_cast<const vfloat4*>(xbar_pre + i);
        const vfloat4 xs = *reinterpret_cast<const vfloat4*>(Xd + i);
        vfloat4 r = 0.95f * xb + 0.05f * xs;
        *reinterpret_cast<vfloat4*>(out_xbar + i) = r;
    } else {
        int j = i - NXB;
        if (j < NU) {
            const vfloat4 u = *reinterpret_cast<const vfloat4*>(u_pot + j);
            const vfloat4 v = *reinterpret_cast<const vfloat4*>(Vpost + j);
            vfloat4 r = 0.9f * u + 0.1f * v;
            *reinterpret_cast<vfloat4*>(out_upot + j) = r;
        } else {
            j -= NU;
            if (j < NU) {
                const vfloat4 u = *reinterpret_cast<const vfloat4*>(u_dep + j);
                const vfloat4 v = *reinterpret_cast<const vfloat4*>(Vpost + j);
                vfloat4 r = 0.8f * u + 0.2f * v;
                *reinterpret_cast<vfloat4*>(out_udep + j) = r;
            }
        }
    }
}

extern "C" void kernel_launch(void* const* d_in, const int* in_sizes, int n_in,
                              void* d_out, int out_size, void* d_ws, size_t ws_size,
                              hipStream_t stream) {
    const float* Xd       = (const float*)d_in[0];
    const float* Xpost    = (const float*)d_in[1];
    const float* Vpost    = (const float*)d_in[2];
    const float* xbar_pre = (const float*)d_in[3];
    const float* u_pot    = (const float*)d_in[4];
    const float* u_dep    = (const float*)d_in[5];
    const float* W        = (const float*)d_in[6];
    const float* A_p      = (const float*)d_in[7];
    const float* A_d      = (const float*)d_in[8];
    const float* dmap     = (const float*)d_in[9];

    float* out = (float*)d_out;
    const size_t BNN = (size_t)BB * NN * NN;      // 33554432
    float* out_W    = out;                        // W pre-update copy
    float* out_Wnew = out + BNN;                  // W_new
    float* out_xbar = out + 2 * BNN;              // (D,B,N)
    float* out_upot = out_xbar + (size_t)DD * BB * NN;
    float* out_udep = out_upot + (size_t)BB * NN;

    // Main: one block per e row.
    clopath_main<<<NN, 256, 0, stream>>>(
        Xd, Xpost, xbar_pre, u_pot, u_dep, W, A_p, A_d, dmap,
        out_W, out_Wnew);

    // Traces: (262144 + 16384 + 16384)/4 = 73728 threads -> 288 blocks.
    clopath_traces<<<288, 256, 0, stream>>>(
        Xd, Vpost, xbar_pre, u_pot, u_dep,
        out_xbar, out_upot, out_udep);
}

// Round 7
// 405.027 us; speedup vs baseline: 1.4214x; 1.4214x over previous
//
#include <hip/hip_runtime.h>

#define DD 16
#define BB 8
#define NN 2048
#define WMAX 2.0f

typedef float vfloat4 __attribute__((ext_vector_type(4)));

// ---------------------------------------------------------------------------
// LDS-staged design. Block = one (e, 1024-wide o chunk); thread owns o4.
//   Stage: 16 x fully-coalesced float4 loads of dmap[d][e][o0:o0+1024] into
//          LDS (64 KB). dmap is fetched from HBM exactly once, at 1KB/instr.
//   Compute: b-outer / d-inner; the 8x reuse of each dmap line is served by
//          LDS (~12cy/instr throughput) instead of L2 (~200cy) — robust to
//          the compiler's register-allocation choices that defeated the
//          register-tiled variants (R1/R2/R5 all re-read dmap 8x from L2).
//   Coefficients xbar_pre[d,b,e] / Xd[d,b,e] are wave-uniform (e from
//          blockIdx) -> scalar loads; accd FMA skipped when Xd==0 (95%).
// ---------------------------------------------------------------------------
__global__ __launch_bounds__(256, 2) void clopath_main(
    const float* __restrict__ Xd,        // (D,B,N)
    const float* __restrict__ Xpost,     // (B,N)
    const float* __restrict__ xbar_pre,  // (D,B,N)
    const float* __restrict__ u_pot,     // (B,N)
    const float* __restrict__ u_dep,     // (B,N)
    const float* __restrict__ W,         // (B,N,N)
    const float* __restrict__ A_p,       // (N,N)
    const float* __restrict__ A_d,       // (N,N)
    const float* __restrict__ dmap,      // (D,N,N)
    float* __restrict__ out_W,           // (B,N,N)  pre-update copy
    float* __restrict__ out_Wnew)        // (B,N,N)
{
    const int e   = (int)blockIdx.x >> 1;              // uniform
    const int o0  = ((int)blockIdx.x & 1) << 10;       // 0 or 1024
    const int tid = (int)threadIdx.x;
    const int o   = o0 + (tid << 2);
    const size_t eo = (size_t)e * NN + o;

    __shared__ float ld[DD][1024];

    // Stage dmap chunk: 16 independent coalesced float4 loads per thread.
#pragma unroll
    for (int d = 0; d < DD; ++d) {
        *reinterpret_cast<vfloat4*>(&ld[d][tid << 2]) =
            *reinterpret_cast<const vfloat4*>(dmap + (size_t)d * NN * NN + eo);
    }

    const vfloat4 ap = *reinterpret_cast<const vfloat4*>(A_p + eo);
    const vfloat4 ad = *reinterpret_cast<const vfloat4*>(A_d + eo);

    __syncthreads();

#pragma unroll
    for (int b = 0; b < BB; ++b) {
        vfloat4 accp = (vfloat4)(0.f);
        vfloat4 accd = (vfloat4)(0.f);
#pragma unroll
        for (int d = 0; d < DD; ++d) {
            const vfloat4 dmv =
                *reinterpret_cast<const vfloat4*>(&ld[d][tid << 2]);
            const float xb = xbar_pre[(d * BB + b) * NN + e];  // s_load
            const float xs = Xd[(d * BB + b) * NN + e];        // s_load
            accp = __builtin_elementwise_fma((vfloat4)(xb), dmv, accp);
            if (xs != 0.f)  // wave-uniform scalar branch; Xd is 95% zero
                accd = __builtin_elementwise_fma((vfloat4)(xs), dmv, accd);
        }

        const int bo = b * NN + o;
        const vfloat4 xp = *reinterpret_cast<const vfloat4*>(Xpost + bo);
        const vfloat4 up = *reinterpret_cast<const vfloat4*>(u_pot + bo);
        const vfloat4 ud = *reinterpret_cast<const vfloat4*>(u_dep + bo);

        const size_t widx = (size_t)b * NN * NN + eo;
        const vfloat4 w4 = *reinterpret_cast<const vfloat4*>(W + widx);

        const vfloat4 gp = xp * __builtin_elementwise_max(up, (vfloat4)(0.f));
        const vfloat4 gd = __builtin_elementwise_max(ud, (vfloat4)(0.f));
        const vfloat4 dw = accp * ap * gp - accd * ad * gd;
        const vfloat4 wn = __builtin_elementwise_min(
            __builtin_elementwise_max(w4 + dw, (vfloat4)(0.f)),
            (vfloat4)(WMAX));

        *reinterpret_cast<vfloat4*>(out_W + widx)    = w4;
        *reinterpret_cast<vfloat4*>(out_Wnew + widx) = wn;
    }
}

// ---------------------------------------------------------------------------
// Trace-filter kernel: xbar_pre_new, u_pot_new, u_dep_new (all tiny).
// ---------------------------------------------------------------------------
__global__ __launch_bounds__(256) void clopath_traces(
    const float* __restrict__ Xd,        // (D,B,N)
    const float* __restrict__ Vpost,     // (B,N)
    const float* __restrict__ xbar_pre,  // (D,B,N)
    const float* __restrict__ u_pot,     // (B,N)
    const float* __restrict__ u_dep,     // (B,N)
    float* __restrict__ out_xbar,        // (D,B,N)
    float* __restrict__ out_upot,        // (B,N)
    float* __restrict__ out_udep)        // (B,N)
{
    const int NXB = DD * BB * NN;  // 262144
    const int NU  = BB * NN;       // 16384
    int i = ((int)blockIdx.x * 256 + (int)threadIdx.x) * 4;
    if (i < NXB) {
        const vfloat4 xb = *reinterpret_cast<const vfloat4*>(xbar_pre + i);
        const vfloat4 xs = *reinterpret_cast<const vfloat4*>(Xd + i);
        vfloat4 r = 0.95f * xb + 0.05f * xs;
        *reinterpret_cast<vfloat4*>(out_xbar + i) = r;
    } else {
        int j = i - NXB;
        if (j < NU) {
            const vfloat4 u = *reinterpret_cast<const vfloat4*>(u_pot + j);
            const vfloat4 v = *reinterpret_cast<const vfloat4*>(Vpost + j);
            vfloat4 r = 0.9f * u + 0.1f * v;
            *reinterpret_cast<vfloat4*>(out_upot + j) = r;
        } else {
            j -= NU;
            if (j < NU) {
                const vfloat4 u = *reinterpret_cast<const vfloat4*>(u_dep + j);
                const vfloat4 v = *reinterpret_cast<const vfloat4*>(Vpost + j);
                vfloat4 r = 0.8f * u + 0.2f * v;
                *reinterpret_cast<vfloat4*>(out_udep + j) = r;
            }
        }
    }
}

extern "C" void kernel_launch(void* const* d_in, const int* in_sizes, int n_in,
                              void* d_out, int out_size, void* d_ws, size_t ws_size,
                              hipStream_t stream) {
    const float* Xd       = (const float*)d_in[0];
    const float* Xpost    = (const float*)d_in[1];
    const float* Vpost    = (const float*)d_in[2];
    const float* xbar_pre = (const float*)d_in[3];
    const float* u_pot    = (const float*)d_in[4];
    const float* u_dep    = (const float*)d_in[5];
    const float* W        = (const float*)d_in[6];
    const float* A_p      = (const float*)d_in[7];
    const float* A_d      = (const float*)d_in[8];
    const float* dmap     = (const float*)d_in[9];

    float* out = (float*)d_out;
    const size_t BNN = (size_t)BB * NN * NN;      // 33554432
    float* out_W    = out;                        // W pre-update copy
    float* out_Wnew = out + BNN;                  // W_new
    float* out_xbar = out + 2 * BNN;              // (D,B,N)
    float* out_upot = out_xbar + (size_t)DD * BB * NN;
    float* out_udep = out_upot + (size_t)BB * NN;

    // Main: 2048 e-rows x 2 o-chunks, 256 threads each.
    clopath_main<<<NN * 2, 256, 0, stream>>>(
        Xd, Xpost, xbar_pre, u_pot, u_dep, W, A_p, A_d, dmap,
        out_W, out_Wnew);

    // Traces: (262144 + 16384 + 16384)/4 = 73728 threads -> 288 blocks.
    clopath_traces<<<288, 256, 0, stream>>>(
        Xd, Vpost, xbar_pre, u_pot, u_dep,
        out_xbar, out_upot, out_udep);
}

// Round 8
// 190.990 us; speedup vs baseline: 3.0143x; 2.1207x over previous
//
#include <hip/hip_runtime.h>

#define DD 16
#define BB 8
#define NN 2048
#define WMAX 2.0f

typedef float vfloat4 __attribute__((ext_vector_type(4)));

// ---------------------------------------------------------------------------
// Batch-split register design.
// Grid: e (2048) x ochunk (2) x bhalf (2) = 8192 blocks, 256 threads.
// Each thread owns (e, o4) for 4 batches b = bh*4 + 0..3.
//   - dm[16] (64 VGPR) + 8 accumulator float4 (32 VGPR) + temps ~= 105 regs,
//     fits the 128-VGPR cap of __launch_bounds__(256,4) -> compiler keeps all
//     16 dmap lines in registers; each dmap line is read ONCE per block.
//   - bh-sibling blocks are adjacent in blockIdx -> co-scheduled -> second
//     block's dmap reads hit L3 (die-level), HBM FETCH stays at the floor.
//   - The 128 wave-uniform coefficients are staged once into 512 B LDS by
//     the first 128 lanes (kills the scattered per-(d,b) s_load chain).
// ---------------------------------------------------------------------------
__global__ __launch_bounds__(256, 4) void clopath_main(
    const float* __restrict__ Xd,        // (D,B,N)
    const float* __restrict__ Xpost,     // (B,N)
    const float* __restrict__ xbar_pre,  // (D,B,N)
    const float* __restrict__ u_pot,     // (B,N)
    const float* __restrict__ u_dep,     // (B,N)
    const float* __restrict__ W,         // (B,N,N)
    const float* __restrict__ A_p,       // (N,N)
    const float* __restrict__ A_d,       // (N,N)
    const float* __restrict__ dmap,      // (D,N,N)
    float* __restrict__ out_W,           // (B,N,N)  pre-update copy
    float* __restrict__ out_Wnew)        // (B,N,N)
{
    const int bx  = (int)blockIdx.x;
    const int e   = bx >> 2;                       // uniform
    const int oc  = (bx >> 1) & 1;                 // o chunk: 0/1
    const int bh  = bx & 1;                        // batch half: 0/1
    const int tid = (int)threadIdx.x;
    const int o   = (oc << 10) + (tid << 2);
    const size_t eo = (size_t)e * NN + o;

    // Stage the 4x16x2 wave-uniform coefficients into LDS (512 B).
    // cf[type][bi][d]: type 0 = xbar_pre, 1 = Xd; b = bh*4 + bi.
    __shared__ float cf[2][4][DD];
    if (tid < 128) {
        const int type = tid >> 6;
        const int bi   = (tid >> 4) & 3;
        const int d    = tid & 15;
        const int b    = bh * 4 + bi;
        const float* src = type ? Xd : xbar_pre;
        cf[type][bi][d] = src[(d * BB + b) * NN + e];
    }

    // All 16 dmap lines -> registers (read once per block).
    vfloat4 dm[DD];
#pragma unroll
    for (int d = 0; d < DD; ++d)
        dm[d] = *reinterpret_cast<const vfloat4*>(
            dmap + (size_t)d * NN * NN + eo);

    const vfloat4 ap = *reinterpret_cast<const vfloat4*>(A_p + eo);
    const vfloat4 ad = *reinterpret_cast<const vfloat4*>(A_d + eo);

    __syncthreads();

#pragma unroll
    for (int bi = 0; bi < 4; ++bi) {
        const int b = bh * 4 + bi;

        vfloat4 accp = (vfloat4)(0.f);
        vfloat4 accd = (vfloat4)(0.f);
#pragma unroll
        for (int d = 0; d < DD; ++d) {
            const float xb = cf[0][bi][d];   // LDS broadcast
            const float xs = cf[1][bi][d];   // LDS broadcast
            accp = __builtin_elementwise_fma((vfloat4)(xb), dm[d], accp);
            accd = __builtin_elementwise_fma((vfloat4)(xs), dm[d], accd);
        }

        const int bo = b * NN + o;
        const vfloat4 xp = *reinterpret_cast<const vfloat4*>(Xpost + bo);
        const vfloat4 up = *reinterpret_cast<const vfloat4*>(u_pot + bo);
        const vfloat4 ud = *reinterpret_cast<const vfloat4*>(u_dep + bo);

        const size_t widx = (size_t)b * NN * NN + eo;
        const vfloat4 w4 = *reinterpret_cast<const vfloat4*>(W + widx);

        const vfloat4 gp = xp * __builtin_elementwise_max(up, (vfloat4)(0.f));
        const vfloat4 gd = __builtin_elementwise_max(ud, (vfloat4)(0.f));
        const vfloat4 dw = accp * ap * gp - accd * ad * gd;
        const vfloat4 wn = __builtin_elementwise_min(
            __builtin_elementwise_max(w4 + dw, (vfloat4)(0.f)),
            (vfloat4)(WMAX));

        *reinterpret_cast<vfloat4*>(out_W + widx)    = w4;
        *reinterpret_cast<vfloat4*>(out_Wnew + widx) = wn;
    }
}

// ---------------------------------------------------------------------------
// Trace-filter kernel: xbar_pre_new, u_pot_new, u_dep_new (all tiny).
// ---------------------------------------------------------------------------
__global__ __launch_bounds__(256) void clopath_traces(
    const float* __restrict__ Xd,        // (D,B,N)
    const float* __restrict__ Vpost,     // (B,N)
    const float* __restrict__ xbar_pre,  // (D,B,N)
    const float* __restrict__ u_pot,     // (B,N)
    const float* __restrict__ u_dep,     // (B,N)
    float* __restrict__ out_xbar,        // (D,B,N)
    float* __restrict__ out_upot,        // (B,N)
    float* __restrict__ out_udep)        // (B,N)
{
    const int NXB = DD * BB * NN;  // 262144
    const int NU  = BB * NN;       // 16384
    int i = ((int)blockIdx.x * 256 + (int)threadIdx.x) * 4;
    if (i < NXB) {
        const vfloat4 xb = *reinterpret_cast<const vfloat4*>(xbar_pre + i);
        const vfloat4 xs = *reinterpret_cast<const vfloat4*>(Xd + i);
        vfloat4 r = 0.95f * xb + 0.05f * xs;
        *reinterpret_cast<vfloat4*>(out_xbar + i) = r;
    } else {
        int j = i - NXB;
        if (j < NU) {
            const vfloat4 u = *reinterpret_cast<const vfloat4*>(u_pot + j);
            const vfloat4 v = *reinterpret_cast<const vfloat4*>(Vpost + j);
            vfloat4 r = 0.9f * u + 0.1f * v;
            *reinterpret_cast<vfloat4*>(out_upot + j) = r;
        } else {
            j -= NU;
            if (j < NU) {
                const vfloat4 u = *reinterpret_cast<const vfloat4*>(u_dep + j);
                const vfloat4 v = *reinterpret_cast<const vfloat4*>(Vpost + j);
                vfloat4 r = 0.8f * u + 0.2f * v;
                *reinterpret_cast<vfloat4*>(out_udep + j) = r;
            }
        }
    }
}

extern "C" void kernel_launch(void* const* d_in, const int* in_sizes, int n_in,
                              void* d_out, int out_size, void* d_ws, size_t ws_size,
                              hipStream_t stream) {
    const float* Xd       = (const float*)d_in[0];
    const float* Xpost    = (const float*)d_in[1];
    const float* Vpost    = (const float*)d_in[2];
    const float* xbar_pre = (const float*)d_in[3];
    const float* u_pot    = (const float*)d_in[4];
    const float* u_dep    = (const float*)d_in[5];
    const float* W        = (const float*)d_in[6];
    const float* A_p      = (const float*)d_in[7];
    const float* A_d      = (const float*)d_in[8];
    const float* dmap     = (const float*)d_in[9];

    float* out = (float*)d_out;
    const size_t BNN = (size_t)BB * NN * NN;      // 33554432
    float* out_W    = out;                        // W pre-update copy
    float* out_Wnew = out + BNN;                  // W_new
    float* out_xbar = out + 2 * BNN;              // (D,B,N)
    float* out_upot = out_xbar + (size_t)DD * BB * NN;
    float* out_udep = out_upot + (size_t)BB * NN;

    // Main: e (2048) x ochunk (2) x bhalf (2) = 8192 blocks.
    clopath_main<<<NN * 4, 256, 0, stream>>>(
        Xd, Xpost, xbar_pre, u_pot, u_dep, W, A_p, A_d, dmap,
        out_W, out_Wnew);

    // Traces: (262144 + 16384 + 16384)/4 = 73728 threads -> 288 blocks.
    clopath_traces<<<288, 256, 0, stream>>>(
        Xd, Vpost, xbar_pre, u_pot, u_dep,
        out_xbar, out_upot, out_udep);
}

// Round 9
// 177.868 us; speedup vs baseline: 3.2367x; 1.0738x over previous
//
#include <hip/hip_runtime.h>

#define DD 16
#define BB 8
#define NN 2048
#define WMAX 2.0f

typedef float vfloat4 __attribute__((ext_vector_type(4)));

// ---------------------------------------------------------------------------
// Bitmask design. dmap is binary {0.0, 1.0}: each thread reads its 16 dmap
// float4s ONCE (coalesced, HBM-floor traffic) and packs them into four
// 16-bit masks (4 VGPRs). The 8x batch reuse is then served by VALU
// recompute (v_bfe + v_cvt + v_fmac per element) instead of L2 re-reads
// (R2: ~200cy each), LDS staging (R7: occupancy collapse), or 64 resident
// VGPRs (R1/R2/R5/R8: allocator refuses).
//   - asm keep-alive on the masks per b-iteration defeats LICM, which would
//     otherwise hoist the 64 bit->float conversions and recreate the wall.
//   - Coefficients xbar_pre[d,b,e] / Xd[d,b,e] are wave-uniform -> s_load,
//     used directly as the SGPR operand of v_fmac.
// ---------------------------------------------------------------------------
__global__ __launch_bounds__(256) void clopath_main(
    const float* __restrict__ Xd,        // (D,B,N)
    const float* __restrict__ Xpost,     // (B,N)
    const float* __restrict__ xbar_pre,  // (D,B,N)
    const float* __restrict__ u_pot,     // (B,N)
    const float* __restrict__ u_dep,     // (B,N)
    const float* __restrict__ W,         // (B,N,N)
    const float* __restrict__ A_p,       // (N,N)
    const float* __restrict__ A_d,       // (N,N)
    const float* __restrict__ dmap,      // (D,N,N)
    float* __restrict__ out_W,           // (B,N,N)  pre-update copy
    float* __restrict__ out_Wnew)        // (B,N,N)
{
    // blocks_per_row = (N/4)/256 = 2
    const int e = (int)blockIdx.x >> 1;                              // uniform
    const int o = ((((int)blockIdx.x & 1) << 8) | (int)threadIdx.x) << 2;
    const size_t eo = (size_t)e * NN + o;

    // Pack 16 dmap lines -> four 16-bit masks (one per o-element).
    unsigned m0 = 0, m1 = 0, m2 = 0, m3 = 0;
#pragma unroll
    for (int d = 0; d < DD; ++d) {
        const vfloat4 v = *reinterpret_cast<const vfloat4*>(
            dmap + (size_t)d * NN * NN + eo);
        m0 |= (unsigned)(v.x != 0.f) << d;
        m1 |= (unsigned)(v.y != 0.f) << d;
        m2 |= (unsigned)(v.z != 0.f) << d;
        m3 |= (unsigned)(v.w != 0.f) << d;
    }

    const vfloat4 ap = *reinterpret_cast<const vfloat4*>(A_p + eo);
    const vfloat4 ad = *reinterpret_cast<const vfloat4*>(A_d + eo);

#pragma unroll
    for (int b = 0; b < BB; ++b) {
        // Keep-alive: make the masks opaque per b-iteration so LICM cannot
        // hoist the 64 bit->float conversions out of the loop (that would
        // recreate the 64-VGPR register wall).
        asm volatile("" : "+v"(m0), "+v"(m1), "+v"(m2), "+v"(m3));

        vfloat4 accp = (vfloat4)(0.f);
        vfloat4 accd = (vfloat4)(0.f);
#pragma unroll
        for (int d = 0; d < DD; ++d) {
            const float xb = xbar_pre[(d * BB + b) * NN + e];  // s_load
            const float xs = Xd[(d * BB + b) * NN + e];        // s_load
            const float f0 = (float)((m0 >> d) & 1u);          // bfe+cvt
            const float f1 = (float)((m1 >> d) & 1u);
            const float f2 = (float)((m2 >> d) & 1u);
            const float f3 = (float)((m3 >> d) & 1u);
            accp.x = fmaf(f0, xb, accp.x);
            accp.y = fmaf(f1, xb, accp.y);
            accp.z = fmaf(f2, xb, accp.z);
            accp.w = fmaf(f3, xb, accp.w);
            accd.x = fmaf(f0, xs, accd.x);
            accd.y = fmaf(f1, xs, accd.y);
            accd.z = fmaf(f2, xs, accd.z);
            accd.w = fmaf(f3, xs, accd.w);
        }

        const int bo = b * NN + o;
        const vfloat4 xp = *reinterpret_cast<const vfloat4*>(Xpost + bo);
        const vfloat4 up = *reinterpret_cast<const vfloat4*>(u_pot + bo);
        const vfloat4 ud = *reinterpret_cast<const vfloat4*>(u_dep + bo);

        const size_t widx = (size_t)b * NN * NN + eo;
        const vfloat4 w4 = *reinterpret_cast<const vfloat4*>(W + widx);

        const vfloat4 gp = xp * __builtin_elementwise_max(up, (vfloat4)(0.f));
        const vfloat4 gd = __builtin_elementwise_max(ud, (vfloat4)(0.f));
        const vfloat4 dw = accp * ap * gp - accd * ad * gd;
        const vfloat4 wn = __builtin_elementwise_min(
            __builtin_elementwise_max(w4 + dw, (vfloat4)(0.f)),
            (vfloat4)(WMAX));

        *reinterpret_cast<vfloat4*>(out_W + widx)    = w4;
        *reinterpret_cast<vfloat4*>(out_Wnew + widx) = wn;
    }
}

// ---------------------------------------------------------------------------
// Trace-filter kernel: xbar_pre_new, u_pot_new, u_dep_new (all tiny).
// ---------------------------------------------------------------------------
__global__ __launch_bounds__(256) void clopath_traces(
    const float* __restrict__ Xd,        // (D,B,N)
    const float* __restrict__ Vpost,     // (B,N)
    const float* __restrict__ xbar_pre,  // (D,B,N)
    const float* __restrict__ u_pot,     // (B,N)
    const float* __restrict__ u_dep,     // (B,N)
    float* __restrict__ out_xbar,        // (D,B,N)
    float* __restrict__ out_upot,        // (B,N)
    float* __restrict__ out_udep)        // (B,N)
{
    const int NXB = DD * BB * NN;  // 262144
    const int NU  = BB * NN;       // 16384
    int i = ((int)blockIdx.x * 256 + (int)threadIdx.x) * 4;
    if (i < NXB) {
        const vfloat4 xb = *reinterpret_cast<const vfloat4*>(xbar_pre + i);
        const vfloat4 xs = *reinterpret_cast<const vfloat4*>(Xd + i);
        vfloat4 r = 0.95f * xb + 0.05f * xs;
        *reinterpret_cast<vfloat4*>(out_xbar + i) = r;
    } else {
        int j = i - NXB;
        if (j < NU) {
            const vfloat4 u = *reinterpret_cast<const vfloat4*>(u_pot + j);
            const vfloat4 v = *reinterpret_cast<const vfloat4*>(Vpost + j);
            vfloat4 r = 0.9f * u + 0.1f * v;
            *reinterpret_cast<vfloat4*>(out_upot + j) = r;
        } else {
            j -= NU;
            if (j < NU) {
                const vfloat4 u = *reinterpret_cast<const vfloat4*>(u_dep + j);
                const vfloat4 v = *reinterpret_cast<const vfloat4*>(Vpost + j);
                vfloat4 r = 0.8f * u + 0.2f * v;
                *reinterpret_cast<vfloat4*>(out_udep + j) = r;
            }
        }
    }
}

extern "C" void kernel_launch(void* const* d_in, const int* in_sizes, int n_in,
                              void* d_out, int out_size, void* d_ws, size_t ws_size,
                              hipStream_t stream) {
    const float* Xd       = (const float*)d_in[0];
    const float* Xpost    = (const float*)d_in[1];
    const float* Vpost    = (const float*)d_in[2];
    const float* xbar_pre = (const float*)d_in[3];
    const float* u_pot    = (const float*)d_in[4];
    const float* u_dep    = (const float*)d_in[5];
    const float* W        = (const float*)d_in[6];
    const float* A_p      = (const float*)d_in[7];
    const float* A_d      = (const float*)d_in[8];
    const float* dmap     = (const float*)d_in[9];

    float* out = (float*)d_out;
    const size_t BNN = (size_t)BB * NN * NN;      // 33554432
    float* out_W    = out;                        // W pre-update copy
    float* out_Wnew = out + BNN;                  // W_new
    float* out_xbar = out + 2 * BNN;              // (D,B,N)
    float* out_upot = out_xbar + (size_t)DD * BB * NN;
    float* out_udep = out_upot + (size_t)BB * NN;

    // Main: N rows x 2 o-chunks, 256 threads each (thread owns o4).
    clopath_main<<<NN * 2, 256, 0, stream>>>(
        Xd, Xpost, xbar_pre, u_pot, u_dep, W, A_p, A_d, dmap,
        out_W, out_Wnew);

    // Traces: (262144 + 16384 + 16384)/4 = 73728 threads -> 288 blocks.
    clopath_traces<<<288, 256, 0, stream>>>(
        Xd, Vpost, xbar_pre, u_pot, u_dep,
        out_xbar, out_upot, out_udep);
}

// Round 10
// 177.404 us; speedup vs baseline: 3.2452x; 1.0026x over previous
//
#include <hip/hip_runtime.h>

#define DD 16
#define BB 8
#define NN 2048
#define WMAX 2.0f

typedef float vfloat4 __attribute__((ext_vector_type(4)));

// ---------------------------------------------------------------------------
// Bitmask design. dmap is binary {0.0, 1.0}: each thread reads its 16 dmap
// float4s ONCE (coalesced, HBM-floor traffic) and packs them into four
// 16-bit masks (4 VGPRs). The 8x batch reuse is then served by VALU
// recompute (v_bfe + v_cvt + v_fmac per element) instead of L2 re-reads
// (R2: ~200cy each), LDS staging (R7: occupancy collapse), or 64 resident
// VGPRs (R1/R2/R5/R8: allocator refuses).
//   - asm keep-alive on the masks per b-iteration defeats LICM, which would
//     otherwise hoist the 64 bit->float conversions and recreate the wall.
//   - Coefficients xbar_pre[d,b,e] / Xd[d,b,e] are wave-uniform -> s_load,
//     used directly as the SGPR operand of v_fmac.
// ---------------------------------------------------------------------------
__global__ __launch_bounds__(256) void clopath_main(
    const float* __restrict__ Xd,        // (D,B,N)
    const float* __restrict__ Xpost,     // (B,N)
    const float* __restrict__ xbar_pre,  // (D,B,N)
    const float* __restrict__ u_pot,     // (B,N)
    const float* __restrict__ u_dep,     // (B,N)
    const float* __restrict__ W,         // (B,N,N)
    const float* __restrict__ A_p,       // (N,N)
    const float* __restrict__ A_d,       // (N,N)
    const float* __restrict__ dmap,      // (D,N,N)
    float* __restrict__ out_W,           // (B,N,N)  pre-update copy
    float* __restrict__ out_Wnew)        // (B,N,N)
{
    // blocks_per_row = (N/4)/256 = 2
    const int e = (int)blockIdx.x >> 1;                              // uniform
    const int o = ((((int)blockIdx.x & 1) << 8) | (int)threadIdx.x) << 2;
    const size_t eo = (size_t)e * NN + o;

    // Pack 16 dmap lines -> four 16-bit masks (one per o-element).
    unsigned m0 = 0, m1 = 0, m2 = 0, m3 = 0;
#pragma unroll
    for (int d = 0; d < DD; ++d) {
        const vfloat4 v = *reinterpret_cast<const vfloat4*>(
            dmap + (size_t)d * NN * NN + eo);
        m0 |= (unsigned)(v.x != 0.f) << d;
        m1 |= (unsigned)(v.y != 0.f) << d;
        m2 |= (unsigned)(v.z != 0.f) << d;
        m3 |= (unsigned)(v.w != 0.f) << d;
    }

    const vfloat4 ap = *reinterpret_cast<const vfloat4*>(A_p + eo);
    const vfloat4 ad = *reinterpret_cast<const vfloat4*>(A_d + eo);

#pragma unroll
    for (int b = 0; b < BB; ++b) {
        // Keep-alive: make the masks opaque per b-iteration so LICM cannot
        // hoist the 64 bit->float conversions out of the loop (that would
        // recreate the 64-VGPR register wall).
        asm volatile("" : "+v"(m0), "+v"(m1), "+v"(m2), "+v"(m3));

        vfloat4 accp = (vfloat4)(0.f);
        vfloat4 accd = (vfloat4)(0.f);
#pragma unroll
        for (int d = 0; d < DD; ++d) {
            const float xb = xbar_pre[(d * BB + b) * NN + e];  // s_load
            const float xs = Xd[(d * BB + b) * NN + e];        // s_load
            const float f0 = (float)((m0 >> d) & 1u);          // bfe+cvt
            const float f1 = (float)((m1 >> d) & 1u);
            const float f2 = (float)((m2 >> d) & 1u);
            const float f3 = (float)((m3 >> d) & 1u);
            accp.x = fmaf(f0, xb, accp.x);
            accp.y = fmaf(f1, xb, accp.y);
            accp.z = fmaf(f2, xb, accp.z);
            accp.w = fmaf(f3, xb, accp.w);
            accd.x = fmaf(f0, xs, accd.x);
            accd.y = fmaf(f1, xs, accd.y);
            accd.z = fmaf(f2, xs, accd.z);
            accd.w = fmaf(f3, xs, accd.w);
        }

        const int bo = b * NN + o;
        const vfloat4 xp = *reinterpret_cast<const vfloat4*>(Xpost + bo);
        const vfloat4 up = *reinterpret_cast<const vfloat4*>(u_pot + bo);
        const vfloat4 ud = *reinterpret_cast<const vfloat4*>(u_dep + bo);

        const size_t widx = (size_t)b * NN * NN + eo;
        const vfloat4 w4 = *reinterpret_cast<const vfloat4*>(W + widx);

        const vfloat4 gp = xp * __builtin_elementwise_max(up, (vfloat4)(0.f));
        const vfloat4 gd = __builtin_elementwise_max(ud, (vfloat4)(0.f));
        const vfloat4 dw = accp * ap * gp - accd * ad * gd;
        const vfloat4 wn = __builtin_elementwise_min(
            __builtin_elementwise_max(w4 + dw, (vfloat4)(0.f)),
            (vfloat4)(WMAX));

        *reinterpret_cast<vfloat4*>(out_W + widx)    = w4;
        *reinterpret_cast<vfloat4*>(out_Wnew + widx) = wn;
    }
}

// ---------------------------------------------------------------------------
// Trace-filter kernel: xbar_pre_new, u_pot_new, u_dep_new (all tiny).
// ---------------------------------------------------------------------------
__global__ __launch_bounds__(256) void clopath_traces(
    const float* __restrict__ Xd,        // (D,B,N)
    const float* __restrict__ Vpost,     // (B,N)
    const float* __restrict__ xbar_pre,  // (D,B,N)
    const float* __restrict__ u_pot,     // (B,N)
    const float* __restrict__ u_dep,     // (B,N)
    float* __restrict__ out_xbar,        // (D,B,N)
    float* __restrict__ out_upot,        // (B,N)
    float* __restrict__ out_udep)        // (B,N)
{
    const int NXB = DD * BB * NN;  // 262144
    const int NU  = BB * NN;       // 16384
    int i = ((int)blockIdx.x * 256 + (int)threadIdx.x) * 4;
    if (i < NXB) {
        const vfloat4 xb = *reinterpret_cast<const vfloat4*>(xbar_pre + i);
        const vfloat4 xs = *reinterpret_cast<const vfloat4*>(Xd + i);
        vfloat4 r = 0.95f * xb + 0.05f * xs;
        *reinterpret_cast<vfloat4*>(out_xbar + i) = r;
    } else {
        int j = i - NXB;
        if (j < NU) {
            const vfloat4 u = *reinterpret_cast<const vfloat4*>(u_pot + j);
            const vfloat4 v = *reinterpret_cast<const vfloat4*>(Vpost + j);
            vfloat4 r = 0.9f * u + 0.1f * v;
            *reinterpret_cast<vfloat4*>(out_upot + j) = r;
        } else {
            j -= NU;
            if (j < NU) {
                const vfloat4 u = *reinterpret_cast<const vfloat4*>(u_dep + j);
                const vfloat4 v = *reinterpret_cast<const vfloat4*>(Vpost + j);
                vfloat4 r = 0.8f * u + 0.2f * v;
                *reinterpret_cast<vfloat4*>(out_udep + j) = r;
            }
        }
    }
}

extern "C" void kernel_launch(void* const* d_in, const int* in_sizes, int n_in,
                              void* d_out, int out_size, void* d_ws, size_t ws_size,
                              hipStream_t stream) {
    const float* Xd       = (const float*)d_in[0];
    const float* Xpost    = (const float*)d_in[1];
    const float* Vpost    = (const float*)d_in[2];
    const float* xbar_pre = (const float*)d_in[3];
    const float* u_pot    = (const float*)d_in[4];
    const float* u_dep    = (const float*)d_in[5];
    const float* W        = (const float*)d_in[6];
    const float* A_p      = (const float*)d_in[7];
    const float* A_d      = (const float*)d_in[8];
    const float* dmap     = (const float*)d_in[9];

    float* out = (float*)d_out;
    const size_t BNN = (size_t)BB * NN * NN;      // 33554432
    float* out_W    = out;                        // W pre-update copy
    float* out_Wnew = out + BNN;                  // W_new
    float* out_xbar = out + 2 * BNN;              // (D,B,N)
    float* out_upot = out_xbar + (size_t)DD * BB * NN;
    float* out_udep = out_upot + (size_t)BB * NN;

    // Main: N rows x 2 o-chunks, 256 threads each (thread owns o4).
    clopath_main<<<NN * 2, 256, 0, stream>>>(
        Xd, Xpost, xbar_pre, u_pot, u_dep, W, A_p, A_d, dmap,
        out_W, out_Wnew);

    // Traces: (262144 + 16384 + 16384)/4 = 73728 threads -> 288 blocks.
    clopath_traces<<<288, 256, 0, stream>>>(
        Xd, Vpost, xbar_pre, u_pot, u_dep,
        out_xbar, out_upot, out_udep);
}

// Round 11
// 163.826 us; speedup vs baseline: 3.5141x; 1.0829x over previous
//
#include <hip/hip_runtime.h>

#define DD 16
#define BB 8
#define NN 2048
#define WMAX 2.0f

typedef float vfloat4 __attribute__((ext_vector_type(4)));

// ---------------------------------------------------------------------------
// Bitmask + LDS-coefficient + W-prefetch design.
//   - dmap is binary {0,1}: read each of the 16 dmap float4s ONCE (coalesced)
//     and pack into four 16-bit masks (4 VGPRs). The 8x batch reuse is VALU
//     recompute (bfe+cvt+fma) — traffic stays at the HBM floor (proven R8).
//   - Coefficients xbar_pre[d,b,e]/Xd[d,b,e]: staged once per block into 1KB
//     LDS by 256 threads (1 scalar each), then read as same-address LDS
//     broadcasts in the b-loop. Kills the 256-scattered-s_load chain that
//     stalled R8 (~200cy L2 latency each).
//   - W[b] prefetch: all 8 float4 loads issued before the b-loop (32 VGPRs;
//     each line needed exactly once). __launch_bounds__(256,4) gives the
//     allocator room (cap 128) — R8's VGPR=32 left no pipelining headroom.
//   - asm keep-alive on masks per b-iteration defeats LICM re-hoisting the
//     64 bit->float conversions (would recreate the register wall).
// ---------------------------------------------------------------------------
__global__ __launch_bounds__(256, 4) void clopath_main(
    const float* __restrict__ Xd,        // (D,B,N)
    const float* __restrict__ Xpost,     // (B,N)
    const float* __restrict__ xbar_pre,  // (D,B,N)
    const float* __restrict__ u_pot,     // (B,N)
    const float* __restrict__ u_dep,     // (B,N)
    const float* __restrict__ W,         // (B,N,N)
    const float* __restrict__ A_p,       // (N,N)
    const float* __restrict__ A_d,       // (N,N)
    const float* __restrict__ dmap,      // (D,N,N)
    float* __restrict__ out_W,           // (B,N,N)  pre-update copy
    float* __restrict__ out_Wnew)        // (B,N,N)
{
    // blocks_per_row = (N/4)/256 = 2
    const int e   = (int)blockIdx.x >> 1;                            // uniform
    const int tid = (int)threadIdx.x;
    const int o   = ((((int)blockIdx.x & 1) << 8) | tid) << 2;
    const size_t eo = (size_t)e * NN + o;

    // --- Coefficient staging: cf[0][idx]=xbar_pre, cf[1][idx]=Xd, idx=d*8+b.
    __shared__ float cf[2][DD * BB];
    {
        const int arr = tid >> 7;          // 0: xbar_pre, 1: Xd
        const int idx = tid & 127;         // = d*BB + b
        const float* src = arr ? Xd : xbar_pre;
        cf[arr][idx] = src[(size_t)idx * NN + e];
    }

    // --- Pack 16 dmap lines -> four 16-bit masks (one per o-element).
    unsigned m0 = 0, m1 = 0, m2 = 0, m3 = 0;
#pragma unroll
    for (int d = 0; d < DD; ++d) {
        const vfloat4 v = *reinterpret_cast<const vfloat4*>(
            dmap + (size_t)d * NN * NN + eo);
        m0 |= (unsigned)(v.x != 0.f) << d;
        m1 |= (unsigned)(v.y != 0.f) << d;
        m2 |= (unsigned)(v.z != 0.f) << d;
        m3 |= (unsigned)(v.w != 0.f) << d;
    }

    const vfloat4 ap = *reinterpret_cast<const vfloat4*>(A_p + eo);
    const vfloat4 ad = *reinterpret_cast<const vfloat4*>(A_d + eo);

    // --- Prefetch all 8 W lines (32 VGPRs; each needed exactly once).
    vfloat4 w4[BB];
#pragma unroll
    for (int b = 0; b < BB; ++b)
        w4[b] = *reinterpret_cast<const vfloat4*>(
            W + (size_t)b * NN * NN + eo);

    __syncthreads();

#pragma unroll
    for (int b = 0; b < BB; ++b) {
        // Keep masks opaque per iteration: block LICM from hoisting the
        // 64 bit->float conversions (register wall).
        asm volatile("" : "+v"(m0), "+v"(m1), "+v"(m2), "+v"(m3));

        vfloat4 accp = (vfloat4)(0.f);
        vfloat4 accd = (vfloat4)(0.f);
#pragma unroll
        for (int d = 0; d < DD; ++d) {
            const float xb = cf[0][d * BB + b];   // LDS broadcast
            const float xs = cf[1][d * BB + b];   // LDS broadcast
            const float f0 = (float)((m0 >> d) & 1u);  // bfe+cvt
            const float f1 = (float)((m1 >> d) & 1u);
            const float f2 = (float)((m2 >> d) & 1u);
            const float f3 = (float)((m3 >> d) & 1u);
            accp.x = fmaf(f0, xb, accp.x);
            accp.y = fmaf(f1, xb, accp.y);
            accp.z = fmaf(f2, xb, accp.z);
            accp.w = fmaf(f3, xb, accp.w);
            accd.x = fmaf(f0, xs, accd.x);
            accd.y = fmaf(f1, xs, accd.y);
            accd.z = fmaf(f2, xs, accd.z);
            accd.w = fmaf(f3, xs, accd.w);
        }

        const int bo = b * NN + o;
        const vfloat4 xp = *reinterpret_cast<const vfloat4*>(Xpost + bo);
        const vfloat4 up = *reinterpret_cast<const vfloat4*>(u_pot + bo);
        const vfloat4 ud = *reinterpret_cast<const vfloat4*>(u_dep + bo);

        const size_t widx = (size_t)b * NN * NN + eo;

        const vfloat4 gp = xp * __builtin_elementwise_max(up, (vfloat4)(0.f));
        const vfloat4 gd = __builtin_elementwise_max(ud, (vfloat4)(0.f));
        const vfloat4 dw = accp * ap * gp - accd * ad * gd;
        const vfloat4 wn = __builtin_elementwise_min(
            __builtin_elementwise_max(w4[b] + dw, (vfloat4)(0.f)),
            (vfloat4)(WMAX));

        *reinterpret_cast<vfloat4*>(out_W + widx)    = w4[b];
        *reinterpret_cast<vfloat4*>(out_Wnew + widx) = wn;
    }
}

// ---------------------------------------------------------------------------
// Trace-filter kernel: xbar_pre_new, u_pot_new, u_dep_new (all tiny).
// ---------------------------------------------------------------------------
__global__ __launch_bounds__(256) void clopath_traces(
    const float* __restrict__ Xd,        // (D,B,N)
    const float* __restrict__ Vpost,     // (B,N)
    const float* __restrict__ xbar_pre,  // (D,B,N)
    const float* __restrict__ u_pot,     // (B,N)
    const float* __restrict__ u_dep,     // (B,N)
    float* __restrict__ out_xbar,        // (D,B,N)
    float* __restrict__ out_upot,        // (B,N)
    float* __restrict__ out_udep)        // (B,N)
{
    const int NXB = DD * BB * NN;  // 262144
    const int NU  = BB * NN;       // 16384
    int i = ((int)blockIdx.x * 256 + (int)threadIdx.x) * 4;
    if (i < NXB) {
        const vfloat4 xb = *reinterpret_cast<const vfloat4*>(xbar_pre + i);
        const vfloat4 xs = *reinterpret_cast<const vfloat4*>(Xd + i);
        vfloat4 r = 0.95f * xb + 0.05f * xs;
        *reinterpret_cast<vfloat4*>(out_xbar + i) = r;
    } else {
        int j = i - NXB;
        if (j < NU) {
            const vfloat4 u = *reinterpret_cast<const vfloat4*>(u_pot + j);
            const vfloat4 v = *reinterpret_cast<const vfloat4*>(Vpost + j);
            vfloat4 r = 0.9f * u + 0.1f * v;
            *reinterpret_cast<vfloat4*>(out_upot + j) = r;
        } else {
            j -= NU;
            if (j < NU) {
                const vfloat4 u = *reinterpret_cast<const vfloat4*>(u_dep + j);
                const vfloat4 v = *reinterpret_cast<const vfloat4*>(Vpost + j);
                vfloat4 r = 0.8f * u + 0.2f * v;
                *reinterpret_cast<vfloat4*>(out_udep + j) = r;
            }
        }
    }
}

extern "C" void kernel_launch(void* const* d_in, const int* in_sizes, int n_in,
                              void* d_out, int out_size, void* d_ws, size_t ws_size,
                              hipStream_t stream) {
    const float* Xd       = (const float*)d_in[0];
    const float* Xpost    = (const float*)d_in[1];
    const float* Vpost    = (const float*)d_in[2];
    const float* xbar_pre = (const float*)d_in[3];
    const float* u_pot    = (const float*)d_in[4];
    const float* u_dep    = (const float*)d_in[5];
    const float* W        = (const float*)d_in[6];
    const float* A_p      = (const float*)d_in[7];
    const float* A_d      = (const float*)d_in[8];
    const float* dmap     = (const float*)d_in[9];

    float* out = (float*)d_out;
    const size_t BNN = (size_t)BB * NN * NN;      // 33554432
    float* out_W    = out;                        // W pre-update copy
    float* out_Wnew = out + BNN;                  // W_new
    float* out_xbar = out + 2 * BNN;              // (D,B,N)
    float* out_upot = out_xbar + (size_t)DD * BB * NN;
    float* out_udep = out_upot + (size_t)BB * NN;

    // Main: N rows x 2 o-chunks, 256 threads each (thread owns o4).
    clopath_main<<<NN * 2, 256, 0, stream>>>(
        Xd, Xpost, xbar_pre, u_pot, u_dep, W, A_p, A_d, dmap,
        out_W, out_Wnew);

    // Traces: (262144 + 16384 + 16384)/4 = 73728 threads -> 288 blocks.
    clopath_traces<<<288, 256, 0, stream>>>(
        Xd, Vpost, xbar_pre, u_pot, u_dep,
        out_xbar, out_upot, out_udep);
}